// Round 7
// baseline (214.509 us; speedup 1.0000x reference)
//
#include <hip/hip_runtime.h>
#include <hip/hip_bf16.h>
#include <math.h>

typedef __hip_bfloat16 bf16;
typedef __attribute__((ext_vector_type(8))) short s8v;   // 8 bf16 (4 VGPRs)
typedef __attribute__((ext_vector_type(4))) float f4v;

#define B_   16
#define T_   1024
#define C_   512
#define M_   (B_*T_)      // 16384
#define NW_  4
#define KWIN 25
#define TCHUNK 16
#define NCHUNK (T_/TCHUNK)   // 64

__device__ __forceinline__ float b2f(bf16 v){ return __bfloat162float(v); }
__device__ __forceinline__ bf16  f2b(float v){ return __float2bfloat16(v); }

// async global->LDS, 16B per lane; LDS dest = wave-uniform base + lane*16
__device__ __forceinline__ void gload16(const bf16* g, bf16* l) {
    __builtin_amdgcn_global_load_lds(
        (const __attribute__((address_space(1))) void*)g,
        (__attribute__((address_space(3))) void*)l, 16, 0, 0);
}

// ---------------------------------------------------------------- K0: coalesced transpose repack (wav w=0..3, ampw at z=4)
// z<4: WWT[o][z*512+c] = wav[(z*512+c)*512+o];  z==4: AWT[o][c] = ampw[c*512+o]
__global__ __launch_bounds__(256) void repack_t_kernel(
    const float* __restrict__ wav, const float* __restrict__ ampw,
    bf16* __restrict__ WWT, bf16* __restrict__ AWT)
{
    __shared__ float tile[32][33];
    const int z = blockIdx.z;
    const int ct = blockIdx.x * 32, ot = blockIdx.y * 32;
    const int tx = threadIdx.x & 31, ty = threadIdx.x >> 5;
    const float* src = (z < 4) ? wav + (size_t)z * 262144 : ampw;
    #pragma unroll
    for (int r = 0; r < 32; r += 8)
        tile[ty + r][tx] = src[(size_t)(ct + ty + r) * 512 + ot + tx];
    __syncthreads();
    #pragma unroll
    for (int r = 0; r < 32; r += 8) {
        int o = ot + ty + r, c = ct + tx;
        bf16 v = f2b(tile[tx][ty + r]);
        if (z < 4) WWT[(size_t)o * 2048 + z * 512 + c] = v;
        else       AWT[(size_t)o * 512 + c] = v;
    }
}

// ---------------------------------------------------------------- K0b: cheby -> power-basis CCT[o][p*512+c] (coalesced transpose)
__global__ __launch_bounds__(256) void repack_cct_kernel(
    const float* __restrict__ cheby,  // [C][C][4] (c,o,d)
    bf16* __restrict__ CCT)           // [512][1536]
{
    __shared__ float t1[32][33], t2[32][33], t3[32][33];
    const int ct = blockIdx.x * 32, ot = blockIdx.y * 32;
    const int tx = threadIdx.x & 31, ty = threadIdx.x >> 5;
    #pragma unroll
    for (int r = 0; r < 32; r += 8) {
        float4 w = *(const float4*)&cheby[(size_t)(ct + ty + r) * 2048 + (size_t)(ot + tx) * 4];
        t1[ty + r][tx] = w.y - 3.f * w.w;
        t2[ty + r][tx] = 2.f * w.z;
        t3[ty + r][tx] = 4.f * w.w;
    }
    __syncthreads();
    #pragma unroll
    for (int r = 0; r < 32; r += 8) {
        int o = ot + ty + r, c = ct + tx;
        size_t base = (size_t)o * 1536 + c;
        CCT[base]        = f2b(t1[tx][ty + r]);
        CCT[base + 512]  = f2b(t2[tx][ty + r]);
        CCT[base + 1024] = f2b(t3[tx][ty + r]);
    }
}

// ---------------------------------------------------------------- K0c: bias0[o] = sum_c (W0 - W2)  (deterministic, no atomics)
__global__ __launch_bounds__(256) void bias0_kernel(
    const float* __restrict__ cheby, float* __restrict__ bias0)
{
    __shared__ float red[8][33];
    const int tx = threadIdx.x & 31, ty = threadIdx.x >> 5;
    const int o = blockIdx.x * 32 + tx;
    float s = 0.f;
    for (int c = ty; c < 512; c += 8) {
        const float* p = &cheby[(size_t)c * 2048 + (size_t)o * 4];
        s += p[0] - p[2];
    }
    red[ty][tx] = s;
    __syncthreads();
    if (ty == 0) {
        float t = 0.f;
        #pragma unroll
        for (int q = 0; q < 8; ++q) t += red[q][tx];
        bias0[o] = t;
    }
}

// ---------------------------------------------------------------- K0d: LDS-tiled transpose w1[1024][512] -> w1T[512][1024]
__global__ __launch_bounds__(256) void transpose_w1_kernel(
    const float* __restrict__ w1, float* __restrict__ w1t)
{
    __shared__ float tile[32][33];
    const int bo = blockIdx.x, bj = blockIdx.y;
    const int tx = threadIdx.x & 31, ty = threadIdx.x >> 5;
    #pragma unroll
    for (int r = 0; r < 32; r += 8)
        tile[ty + r][tx] = w1[(size_t)(bj * 32 + ty + r) * 512 + bo * 32 + tx];
    __syncthreads();
    #pragma unroll
    for (int r = 0; r < 32; r += 8)
        w1t[(size_t)(bo * 32 + ty + r) * 1024 + bj * 32 + tx] = tile[tx][ty + r];
}

// ---------------------------------------------------------------- K1: causal MA + dwconv3 x3 + power basis + pools
__global__ __launch_bounds__(256) void decomp_kernel(
    const float* __restrict__ x,
    const float* __restrict__ tcw, const float* __restrict__ tcb,
    const float* __restrict__ scw, const float* __restrict__ scb,
    const float* __restrict__ lcw, const float* __restrict__ lcb,
    bf16* __restrict__ xt_pow,    // [M][1536] : [tanh | tanh^2 | tanh^3]
    bf16* __restrict__ sctx,      // [M][512]
    float* __restrict__ slope_part, float* __restrict__ value_part)
{
    const int c     = threadIdx.x * 2;
    const int chunk = blockIdx.x;               // 64 chunks
    const int b     = blockIdx.y;               // 16
    const int t0    = chunk * TCHUNK;
    const float* xb = x + (size_t)b * T_ * C_ + c;

    auto X = [&](int i) -> float2 {
        i = i < 0 ? 0 : (i > T_ - 1 ? T_ - 1 : i);
        return *(const float2*)&xb[(size_t)i * C_];
    };

    float w0t[2], w1t_[2], w2t[2], bt[2], w0s[2], w1s[2], w2s[2], bs[2], w0l[2], w1l[2], w2l[2], bl[2];
    #pragma unroll
    for (int e = 0; e < 2; ++e) {
        w0t[e]=tcw[(c+e)*3+0]; w1t_[e]=tcw[(c+e)*3+1]; w2t[e]=tcw[(c+e)*3+2]; bt[e]=tcb[c+e];
        w0s[e]=scw[(c+e)*3+0]; w1s[e]=scw[(c+e)*3+1]; w2s[e]=scw[(c+e)*3+2]; bs[e]=scb[c+e];
        w0l[e]=lcw[(c+e)*3+0]; w1l[e]=lcw[(c+e)*3+1]; w2l[e]=lcw[(c+e)*3+2]; bl[e]=lcb[c+e];
    }

    const float inv = 1.f / KWIN;
    int j0 = (t0 > 0) ? (t0 - 1) : 0;
    float S[2] = {0.f, 0.f};
    #pragma unroll
    for (int i = j0 - (KWIN - 1); i <= j0; ++i) { float2 v = X(i); S[0] += v.x; S[1] += v.y; }
    float trm[2], tr0[2], xm[2], x0v[2], sAcc[2] = {0.f,0.f}, vAcc[2] = {0.f,0.f};
    trm[0] = S[0] * inv; trm[1] = S[1] * inv;
    if (t0 > 0) {
        float2 a = X(t0), d = X(t0 - KWIN);
        S[0] += a.x - d.x; S[1] += a.y - d.y;
        tr0[0] = S[0] * inv; tr0[1] = S[1] * inv;
    } else { tr0[0] = trm[0]; tr0[1] = trm[1]; }
    { float2 v = X(t0 - 1); xm[0] = v.x; xm[1] = v.y; }
    { float2 v = X(t0);     x0v[0] = v.x; x0v[1] = v.y; }

    #pragma unroll
    for (int t = t0; t < t0 + TCHUNK; ++t) {
        float trp[2], xp[2];
        int tn = t + 1;
        if (tn <= T_ - 1) {
            float2 a = X(tn), d = X(tn - KWIN);
            S[0] += a.x - d.x; S[1] += a.y - d.y;
            trp[0] = S[0] * inv; trp[1] = S[1] * inv;
            xp[0] = a.x; xp[1] = a.y;
        } else {
            trp[0] = tr0[0]; trp[1] = tr0[1];
            xp[0] = x0v[0];  xp[1] = x0v[1];
        }
        union { bf16 h[2]; unsigned u; } u1, u2, u3, usc;
        #pragma unroll
        for (int e = 0; e < 2; ++e) {
            float tctx = w0t[e]*trm[e] + w1t_[e]*tr0[e] + w2t[e]*trp[e] + bt[e];
            float sm = xm[e]-trm[e], s0 = x0v[e]-tr0[e], sp = xp[e]-trp[e];
            float sv = w0s[e]*sm + w1s[e]*s0 + w2s[e]*sp + bs[e];
            float sl = w0l[e]*trm[e] + w1l[e]*tr0[e] + w2l[e]*trp[e] + bl[e];
            sAcc[e] += sl; vAcc[e] += tr0[e];
            float th = tanhf(tctx);
            u1.h[e] = f2b(th); u2.h[e] = f2b(th * th); u3.h[e] = f2b(th * th * th);
            usc.h[e] = f2b(sv);
            trm[e] = tr0[e]; tr0[e] = trp[e]; xm[e] = x0v[e]; x0v[e] = xp[e];
        }
        size_t m = (size_t)b * T_ + t;
        size_t prow = m * 1536 + c;
        *(unsigned*)&xt_pow[prow]        = u1.u;
        *(unsigned*)&xt_pow[prow + 512]  = u2.u;
        *(unsigned*)&xt_pow[prow + 1024] = u3.u;
        *(unsigned*)&sctx[m * C_ + c]    = usc.u;
    }
    int pidx = (chunk * B_ + b) * C_ + c;
    *(float2*)&slope_part[pidx] = make_float2(sAcc[0], sAcc[1]);
    *(float2*)&value_part[pidx] = make_float2(vAcc[0], vAcc[1]);
}

// ---------------------------------------------------------------- K2a: pool reduce -> pc[16][1024]
__global__ __launch_bounds__(256) void pool_kernel(
    const float* __restrict__ slope_part, const float* __restrict__ value_part,
    float* __restrict__ pc)
{
    int idx = blockIdx.x * 256 + threadIdx.x;   // 16384
    int b = idx >> 10, j = idx & 1023;
    int c = j & 511;
    const float* src = (j < 512) ? slope_part : value_part;
    float s = 0.f;
    #pragma unroll 8
    for (int ch = 0; ch < NCHUNK; ++ch) s += src[(ch * B_ + b) * C_ + c];
    pc[idx] = s * (1.f / T_);
}

// ---------------------------------------------------------------- K2b: h = silu(pc @ w1 + b1); 1 block per o
__global__ __launch_bounds__(256) void hyper1_kernel(
    const float* __restrict__ pc, const float* __restrict__ w1t,
    const float* __restrict__ b1, float* __restrict__ h)
{
    const int o = blockIdx.x, t = threadIdx.x;
    const float4 w = *(const float4*)&w1t[(size_t)o * 1024 + t * 4];
    float acc[16];
    #pragma unroll
    for (int b = 0; b < 16; ++b) {
        float4 p = *(const float4*)&pc[(size_t)b * 1024 + t * 4];
        acc[b] = w.x * p.x + w.y * p.y + w.z * p.z + w.w * p.w;
    }
    #pragma unroll
    for (int off = 32; off >= 1; off >>= 1)
        #pragma unroll
        for (int b = 0; b < 16; ++b) acc[b] += __shfl_down(acc[b], off);
    __shared__ float red[4][16];
    int lane = t & 63, wv = t >> 6;
    if (lane == 0)
        #pragma unroll
        for (int b = 0; b < 16; ++b) red[wv][b] = acc[b];
    __syncthreads();
    if (t < 16) {
        float s = red[0][t] + red[1][t] + red[2][t] + red[3][t] + b1[o];
        h[(size_t)t * 512 + o] = s / (1.f + expf(-s));
    }
}

// ---------------------------------------------------------------- K2c: params -> dyn_a, dyn_b
__global__ __launch_bounds__(128) void hyper2_kernel(
    const float* __restrict__ h, const float* __restrict__ w2,
    const float* __restrict__ b2, float* __restrict__ dyn_a, float* __restrict__ dyn_b)
{
    __shared__ float pp[16][8];
    const int t = threadIdx.x, b = t >> 3, o = t & 7;
    float acc = b2[o];
    #pragma unroll 4
    for (int j = 0; j < 512; ++j) acc += h[(size_t)b * 512 + j] * w2[j * 8 + o];
    pp[b][o] = acc;
    __syncthreads();
    if (t < 64) {
        int bb = t >> 2, w = t & 3;
        float pa = pp[bb][2 * w], pb = pp[bb][2 * w + 1];
        float sp = fmaxf(pa, 0.f) + log1pf(expf(-fabsf(pa)));
        dyn_a[bb * NW_ + w] = sp + 0.01f;
        dyn_b[bb * NW_ + w] = (1.f / (1.f + expf(-pb))) * (float)T_;
    }
}

// ---------------------------------------------------------------- K2d: psi[m][w] Ricker wavelet
__global__ __launch_bounds__(256) void psi_kernel(
    const float* __restrict__ dyn_a, const float* __restrict__ dyn_b,
    float* __restrict__ psi)
{
    int idx = blockIdx.x * 256 + threadIdx.x;
    int w = idx & 3, m = idx >> 2;
    int b = m >> 10, t = m & 1023;
    float z = ((float)t - dyn_b[b * 4 + w]) / dyn_a[b * 4 + w];
    float z2 = z * z;
    psi[idx] = (1.f - z2) * expf(-0.5f * z2);
}

// ---------------------------------------------------------------- GEMM: 8-wave 128x256 tile, BK=64, N=512
// KIND=0 (fused, 512 blocks): mode0 tout = xt_pow[M][1536] @ CCT^T + bias0;
//                             mode1 sout = (psi-scaled sctx)[M][2048] @ WWT^T
// KIND=1 (amp, 256 blocks):   ampin = tout[M][512] @ AWT^T
template<int KIND>
__global__ __launch_bounds__(512, 4) void gemm_kernel(
    const bf16* __restrict__ pA0, const bf16* __restrict__ pA1,
    const bf16* __restrict__ pB0, const bf16* __restrict__ pB1,
    const float* __restrict__ psi, const float* __restrict__ bias0,
    bf16* __restrict__ pC0, bf16* __restrict__ pC1)
{
    __shared__ bf16 lA[128 * 64];   // 16 KB
    __shared__ bf16 lB[256 * 64];   // 32 KB

    const int lin = blockIdx.x;
    int mode, mb, nb;
    if (KIND == 0) {
        int swz = ((lin & 7) << 6) + (lin >> 3);   // bijective, 512/8=64
        mode = swz & 1; int rem = swz >> 1;
        nb = rem & 1; mb = rem >> 1;
    } else {
        int swz = ((lin & 7) << 5) + (lin >> 3);   // bijective, 256/8=32
        mode = 0; nb = swz & 1; mb = swz >> 1;
    }
    const int m0 = mb << 7, n0 = nb << 8;

    const bf16* Ap; const bf16* Bp; bf16* Cp; int K, lda;
    if (KIND == 0) {
        if (mode == 0) { Ap = pA0; lda = 1536; Bp = pB0; Cp = pC0; K = 1536; }
        else           { Ap = pA1; lda = 512;  Bp = pB1; Cp = pC1; K = 2048; }
    } else { Ap = pA0; lda = 512; Bp = pB0; Cp = pC0; K = 512; }

    const int tid = threadIdx.x;
    const int lane = tid & 63, wvi = tid >> 6;
    const int wr = wvi >> 2, wc = wvi & 3;         // 2m x 4n waves of 64x64
    const int r16 = lane & 15, g = lane >> 4;
    const int row8 = lane >> 3, sl8 = lane & 7;

    // mode1 reg-staging ids: 4 threads per row, 16 cols each
    const int arow = tid >> 2, quad = tid & 3;
    float4 p4 = make_float4(0.f, 0.f, 0.f, 0.f);
    if (KIND == 0 && mode == 1) p4 = *(const float4*)&psi[(size_t)(m0 + arow) * 4];

    f4v acc[4][4];
    #pragma unroll
    for (int i = 0; i < 4; ++i)
        #pragma unroll
        for (int j = 0; j < 4; ++j) acc[i][j] = (f4v)0.f;

    const int nK = K >> 6;
    for (int kt = 0; kt < nK; ++kt) {
        const int k0 = kt << 6;

        // ---- B stage [256 n][64 k]: 4 gload16/thread ----
        #pragma unroll
        for (int c2 = 0; c2 < 4; ++c2) {
            int rb = c2 * 8 + wvi;
            int r = rb * 8 + row8;
            int ls = sl8 ^ (r & 7);
            gload16(Bp + (size_t)(n0 + r) * K + k0 + ls * 8, &lB[rb * 512]);
        }

        if (KIND == 1 || mode == 0) {
            // ---- A stage [128][64]: 2 gload16/thread ----
            #pragma unroll
            for (int c2 = 0; c2 < 2; ++c2) {
                int ra = c2 * 8 + wvi;
                int r = ra * 8 + row8;
                int ls = sl8 ^ (r & 7);
                gload16(Ap + (size_t)(m0 + r) * lda + k0 + ls * 8, &lA[ra * 512]);
            }
            __syncthreads();   // drain vmcnt: A+B resident; prev reads done
        } else {
            // ---- A stage: reg-load sctx, psi-scale, swizzled ds_write ----
            const int wsel = k0 >> 9;
            const float sc = wsel == 0 ? p4.x : wsel == 1 ? p4.y : wsel == 2 ? p4.z : p4.w;
            const bf16* srcA = Ap + (size_t)(m0 + arow) * 512 + (k0 & 511) + quad * 16;
            s8v av[2];
            av[0] = *(const s8v*)srcA;
            av[1] = *(const s8v*)(srcA + 8);
            __syncthreads();   // prev-iter LDS reads done; B vmcnt drained
            #pragma unroll
            for (int j2 = 0; j2 < 2; ++j2) {
                s8v ov;
                #pragma unroll
                for (int e = 0; e < 8; ++e)
                    ((bf16*)&ov)[e] = f2b(b2f(((const bf16*)&av[j2])[e]) * sc);
                int q = quad * 2 + j2;
                *(s8v*)&lA[arow * 64 + ((q ^ (arow & 7)) << 3)] = ov;
            }
            __syncthreads();   // ds_writes visible
        }

        // ---- compute: 2 mfma-K steps of 32 ----
        #pragma unroll
        for (int ks = 0; ks < 2; ++ks) {
            s8v afr[4], bfr[4];
            #pragma unroll
            for (int i = 0; i < 4; ++i) {
                int ar = wr * 64 + i * 16 + r16;
                afr[i] = *(const s8v*)((const char*)lA + ar * 128 + (((ks * 4 + g) ^ (ar & 7)) << 4));
            }
            #pragma unroll
            for (int j = 0; j < 4; ++j) {
                int br = wc * 64 + j * 16 + r16;
                bfr[j] = *(const s8v*)((const char*)lB + br * 128 + (((ks * 4 + g) ^ (br & 7)) << 4));
            }
            #pragma unroll
            for (int i = 0; i < 4; ++i)
                #pragma unroll
                for (int j = 0; j < 4; ++j)
                    acc[i][j] = __builtin_amdgcn_mfma_f32_16x16x32_bf16(afr[i], bfr[j], acc[i][j], 0, 0, 0);
        }
        __syncthreads();       // reads done before next-iter staging
    }

    // ---- C write (D: col=lane&15, row=(lane>>4)*4+r), + bias on KIND0/mode0 ----
    #pragma unroll
    for (int i = 0; i < 4; ++i)
        #pragma unroll
        for (int j = 0; j < 4; ++j) {
            int cc = n0 + wc * 64 + j * 16 + r16;
            float bb = (KIND == 0 && mode == 0) ? bias0[cc] : 0.f;
            #pragma unroll
            for (int r = 0; r < 4; ++r) {
                int rr = m0 + wr * 64 + i * 16 + g * 4 + r;
                Cp[(size_t)rr * 512 + cc] = f2b(acc[i][j][r] + bb);
            }
        }
}

// ---------------------------------------------------------------- K6: amp gate + residual + LayerNorm
__global__ __launch_bounds__(256) void epilogue_kernel(
    const float* __restrict__ x,   const bf16* __restrict__ tout,
    const bf16* __restrict__ sout, const bf16* __restrict__ ampin,
    const float* __restrict__ ampb, const float* __restrict__ gamma,
    const float* __restrict__ beta, float* __restrict__ out)
{
    __shared__ float red[8];
    const int m = blockIdx.x, tid = threadIdx.x;
    const size_t base = (size_t)m * 512;

    float y[2];
    #pragma unroll
    for (int q = 0; q < 2; ++q) {
        int c = tid + q * 256;
        float to = b2f(tout[base + c]);
        float so = b2f(sout[base + c]);
        float ai = b2f(ampin[base + c]) + ampb[c];
        float amp = 2.f / (1.f + expf(-ai));
        y[q] = to + so * amp + x[base + c];
    }
    float s = y[0] + y[1], sq = y[0] * y[0] + y[1] * y[1];
    #pragma unroll
    for (int off = 32; off >= 1; off >>= 1) {
        s  += __shfl_down(s, off);
        sq += __shfl_down(sq, off);
    }
    int lane = tid & 63, wv = tid >> 6;
    if (lane == 0) { red[wv * 2] = s; red[wv * 2 + 1] = sq; }
    __syncthreads();
    if (tid == 0) {
        float ts = 0.f, tq = 0.f;
        #pragma unroll
        for (int i = 0; i < 4; ++i) { ts += red[i * 2]; tq += red[i * 2 + 1]; }
        red[0] = ts; red[1] = tq;
    }
    __syncthreads();
    float mu  = red[0] * (1.f / 512.f);
    float var = red[1] * (1.f / 512.f) - mu * mu;
    float rstd = rsqrtf(var + 1e-5f);
    #pragma unroll
    for (int q = 0; q < 2; ++q) {
        int c = tid + q * 256;
        out[base + c] = (y[q] - mu) * rstd * gamma[c] + beta[c];
    }
}

// ----------------------------------------------------------------
extern "C" void kernel_launch(void* const* d_in, const int* in_sizes, int n_in,
                              void* d_out, int out_size, void* d_ws, size_t ws_size,
                              hipStream_t stream)
{
    const float* x     = (const float*)d_in[0];
    const float* tcw   = (const float*)d_in[1];
    const float* tcb   = (const float*)d_in[2];
    const float* scw   = (const float*)d_in[3];
    const float* scb   = (const float*)d_in[4];
    const float* lcw   = (const float*)d_in[5];
    const float* lcb   = (const float*)d_in[6];
    const float* cheby = (const float*)d_in[7];
    const float* hw1   = (const float*)d_in[8];
    const float* hb1   = (const float*)d_in[9];
    const float* hw2   = (const float*)d_in[10];
    const float* hb2   = (const float*)d_in[11];
    const float* ampw  = (const float*)d_in[12];
    const float* ampb  = (const float*)d_in[13];
    const float* wav   = (const float*)d_in[14];
    const float* lng   = (const float*)d_in[15];
    const float* lnb   = (const float*)d_in[16];
    float* out = (float*)d_out;

    char* ws = (char*)d_ws;
    size_t off = 0;
    auto alloc = [&](size_t bytes) -> char* {
        char* p = ws + off;
        off += (bytes + 255) & ~(size_t)255;
        return p;
    };
    bf16*  xt_pow     = (bf16*)alloc((size_t)M_ * 1536 * 2);
    bf16*  sctx       = (bf16*)alloc((size_t)M_ * 512 * 2);
    bf16*  tout       = (bf16*)alloc((size_t)M_ * 512 * 2);
    bf16*  sout       = (bf16*)alloc((size_t)M_ * 512 * 2);
    bf16*  ampin      = (bf16*)alloc((size_t)M_ * 512 * 2);
    bf16*  CCT        = (bf16*)alloc((size_t)512 * 1536 * 2);
    bf16*  WWT        = (bf16*)alloc((size_t)512 * 2048 * 2);
    bf16*  AWT        = (bf16*)alloc((size_t)512 * 512 * 2);
    float* W1T        = (float*)alloc((size_t)512 * 1024 * 4);
    float* bias0      = (float*)alloc(512 * 4);
    float* slope_part = (float*)alloc((size_t)NCHUNK * B_ * C_ * 4);
    float* value_part = (float*)alloc((size_t)NCHUNK * B_ * C_ * 4);
    float* pc         = (float*)alloc(B_ * 1024 * 4);
    float* hbuf       = (float*)alloc(B_ * C_ * 4);
    float* dyn_a      = (float*)alloc(B_ * NW_ * 4);
    float* dyn_b      = (float*)alloc(B_ * NW_ * 4);
    float* psi        = (float*)alloc((size_t)M_ * NW_ * 4);

    repack_t_kernel<<<dim3(16, 16, 5), 256, 0, stream>>>(wav, ampw, WWT, AWT);
    repack_cct_kernel<<<dim3(16, 16), 256, 0, stream>>>(cheby, CCT);
    bias0_kernel<<<16, 256, 0, stream>>>(cheby, bias0);
    transpose_w1_kernel<<<dim3(16, 32), 256, 0, stream>>>(hw1, W1T);
    decomp_kernel<<<dim3(NCHUNK, B_), 256, 0, stream>>>(x, tcw, tcb, scw, scb, lcw, lcb,
                                                        xt_pow, sctx, slope_part, value_part);
    pool_kernel<<<64, 256, 0, stream>>>(slope_part, value_part, pc);
    hyper1_kernel<<<512, 256, 0, stream>>>(pc, W1T, hb1, hbuf);
    hyper2_kernel<<<1, 128, 0, stream>>>(hbuf, hw2, hb2, dyn_a, dyn_b);
    psi_kernel<<<256, 256, 0, stream>>>(dyn_a, dyn_b, psi);
    gemm_kernel<0><<<512, 512, 0, stream>>>(xt_pow, sctx, CCT, WWT, psi, bias0, tout, sout);
    gemm_kernel<1><<<256, 512, 0, stream>>>(tout, nullptr, AWT, nullptr, nullptr, nullptr, ampin, nullptr);
    epilogue_kernel<<<16384, 256, 0, stream>>>(x, tout, sout, ampin, ampb, lng, lnb, out);
}

// Round 8
// 207.245 us; speedup vs baseline: 1.0351x; 1.0351x over previous
//
#include <hip/hip_runtime.h>
#include <hip/hip_bf16.h>
#include <math.h>

typedef __hip_bfloat16 bf16;
typedef __attribute__((ext_vector_type(8))) short s8v;   // 8 bf16 (4 VGPRs)
typedef __attribute__((ext_vector_type(4))) float f4v;

#define B_   16
#define T_   1024
#define C_   512
#define M_   (B_*T_)      // 16384
#define NW_  4
#define KWIN 25
#define TCHUNK 16
#define NCHUNK (T_/TCHUNK)   // 64

__device__ __forceinline__ float b2f(bf16 v){ return __bfloat162float(v); }
__device__ __forceinline__ bf16  f2b(float v){ return __float2bfloat16(v); }

// async global->LDS, 16B per lane; LDS dest = wave-uniform base + lane*16
__device__ __forceinline__ void gload16(const bf16* g, bf16* l) {
    __builtin_amdgcn_global_load_lds(
        (const __attribute__((address_space(1))) void*)g,
        (__attribute__((address_space(3))) void*)l, 16, 0, 0);
}

// ---------------------------------------------------------------- K0: coalesced transpose repack (wav w=0..3, ampw at z=4)
__global__ __launch_bounds__(256) void repack_t_kernel(
    const float* __restrict__ wav, const float* __restrict__ ampw,
    bf16* __restrict__ WWT, bf16* __restrict__ AWT)
{
    __shared__ float tile[32][33];
    const int z = blockIdx.z;
    const int ct = blockIdx.x * 32, ot = blockIdx.y * 32;
    const int tx = threadIdx.x & 31, ty = threadIdx.x >> 5;
    const float* src = (z < 4) ? wav + (size_t)z * 262144 : ampw;
    #pragma unroll
    for (int r = 0; r < 32; r += 8)
        tile[ty + r][tx] = src[(size_t)(ct + ty + r) * 512 + ot + tx];
    __syncthreads();
    #pragma unroll
    for (int r = 0; r < 32; r += 8) {
        int o = ot + ty + r, c = ct + tx;
        bf16 v = f2b(tile[tx][ty + r]);
        if (z < 4) WWT[(size_t)o * 2048 + z * 512 + c] = v;
        else       AWT[(size_t)o * 512 + c] = v;
    }
}

// ---------------------------------------------------------------- K0b: cheby -> power-basis CCT[o][p*512+c] (coalesced transpose)
__global__ __launch_bounds__(256) void repack_cct_kernel(
    const float* __restrict__ cheby,  // [C][C][4] (c,o,d)
    bf16* __restrict__ CCT)           // [512][1536]
{
    __shared__ float t1[32][33], t2[32][33], t3[32][33];
    const int ct = blockIdx.x * 32, ot = blockIdx.y * 32;
    const int tx = threadIdx.x & 31, ty = threadIdx.x >> 5;
    #pragma unroll
    for (int r = 0; r < 32; r += 8) {
        float4 w = *(const float4*)&cheby[(size_t)(ct + ty + r) * 2048 + (size_t)(ot + tx) * 4];
        t1[ty + r][tx] = w.y - 3.f * w.w;
        t2[ty + r][tx] = 2.f * w.z;
        t3[ty + r][tx] = 4.f * w.w;
    }
    __syncthreads();
    #pragma unroll
    for (int r = 0; r < 32; r += 8) {
        int o = ot + ty + r, c = ct + tx;
        size_t base = (size_t)o * 1536 + c;
        CCT[base]        = f2b(t1[tx][ty + r]);
        CCT[base + 512]  = f2b(t2[tx][ty + r]);
        CCT[base + 1024] = f2b(t3[tx][ty + r]);
    }
}

// ---------------------------------------------------------------- K0c: bias0[o] = sum_c (W0 - W2)
__global__ __launch_bounds__(256) void bias0_kernel(
    const float* __restrict__ cheby, float* __restrict__ bias0)
{
    __shared__ float red[8][33];
    const int tx = threadIdx.x & 31, ty = threadIdx.x >> 5;
    const int o = blockIdx.x * 32 + tx;
    float s = 0.f;
    for (int c = ty; c < 512; c += 8) {
        const float* p = &cheby[(size_t)c * 2048 + (size_t)o * 4];
        s += p[0] - p[2];
    }
    red[ty][tx] = s;
    __syncthreads();
    if (ty == 0) {
        float t = 0.f;
        #pragma unroll
        for (int q = 0; q < 8; ++q) t += red[q][tx];
        bias0[o] = t;
    }
}

// ---------------------------------------------------------------- K0d: LDS-tiled transpose w1[1024][512] -> w1T[512][1024]
__global__ __launch_bounds__(256) void transpose_w1_kernel(
    const float* __restrict__ w1, float* __restrict__ w1t)
{
    __shared__ float tile[32][33];
    const int bo = blockIdx.x, bj = blockIdx.y;
    const int tx = threadIdx.x & 31, ty = threadIdx.x >> 5;
    #pragma unroll
    for (int r = 0; r < 32; r += 8)
        tile[ty + r][tx] = w1[(size_t)(bj * 32 + ty + r) * 512 + bo * 32 + tx];
    __syncthreads();
    #pragma unroll
    for (int r = 0; r < 32; r += 8)
        w1t[(size_t)(bo * 32 + ty + r) * 1024 + bj * 32 + tx] = tile[tx][ty + r];
}

// ---------------------------------------------------------------- K1: causal MA + dwconv3 x3 + pools
__global__ __launch_bounds__(256) void decomp_kernel(
    const float* __restrict__ x,
    const float* __restrict__ tcw, const float* __restrict__ tcb,
    const float* __restrict__ scw, const float* __restrict__ scb,
    const float* __restrict__ lcw, const float* __restrict__ lcb,
    bf16* __restrict__ xt,        // tanh(trend_ctx) [M][512]
    bf16* __restrict__ sctx,      // [M][512]
    float* __restrict__ slope_part, float* __restrict__ value_part)
{
    const int c     = threadIdx.x * 2;
    const int chunk = blockIdx.x;               // 64 chunks
    const int b     = blockIdx.y;               // 16
    const int t0    = chunk * TCHUNK;
    const float* xb = x + (size_t)b * T_ * C_ + c;

    auto X = [&](int i) -> float2 {
        i = i < 0 ? 0 : (i > T_ - 1 ? T_ - 1 : i);
        return *(const float2*)&xb[(size_t)i * C_];
    };

    float w0t[2], w1t_[2], w2t[2], bt[2], w0s[2], w1s[2], w2s[2], bs[2], w0l[2], w1l[2], w2l[2], bl[2];
    #pragma unroll
    for (int e = 0; e < 2; ++e) {
        w0t[e]=tcw[(c+e)*3+0]; w1t_[e]=tcw[(c+e)*3+1]; w2t[e]=tcw[(c+e)*3+2]; bt[e]=tcb[c+e];
        w0s[e]=scw[(c+e)*3+0]; w1s[e]=scw[(c+e)*3+1]; w2s[e]=scw[(c+e)*3+2]; bs[e]=scb[c+e];
        w0l[e]=lcw[(c+e)*3+0]; w1l[e]=lcw[(c+e)*3+1]; w2l[e]=lcw[(c+e)*3+2]; bl[e]=lcb[c+e];
    }

    const float inv = 1.f / KWIN;
    int j0 = (t0 > 0) ? (t0 - 1) : 0;
    float S[2] = {0.f, 0.f};
    #pragma unroll
    for (int i = j0 - (KWIN - 1); i <= j0; ++i) { float2 v = X(i); S[0] += v.x; S[1] += v.y; }
    float trm[2], tr0[2], xm[2], x0v[2], sAcc[2] = {0.f,0.f}, vAcc[2] = {0.f,0.f};
    trm[0] = S[0] * inv; trm[1] = S[1] * inv;
    if (t0 > 0) {
        float2 a = X(t0), d = X(t0 - KWIN);
        S[0] += a.x - d.x; S[1] += a.y - d.y;
        tr0[0] = S[0] * inv; tr0[1] = S[1] * inv;
    } else { tr0[0] = trm[0]; tr0[1] = trm[1]; }
    { float2 v = X(t0 - 1); xm[0] = v.x; xm[1] = v.y; }
    { float2 v = X(t0);     x0v[0] = v.x; x0v[1] = v.y; }

    #pragma unroll
    for (int t = t0; t < t0 + TCHUNK; ++t) {
        float trp[2], xp[2];
        int tn = t + 1;
        if (tn <= T_ - 1) {
            float2 a = X(tn), d = X(tn - KWIN);
            S[0] += a.x - d.x; S[1] += a.y - d.y;
            trp[0] = S[0] * inv; trp[1] = S[1] * inv;
            xp[0] = a.x; xp[1] = a.y;
        } else {
            trp[0] = tr0[0]; trp[1] = tr0[1];
            xp[0] = x0v[0];  xp[1] = x0v[1];
        }
        union { bf16 h[2]; unsigned u; } u1, usc;
        #pragma unroll
        for (int e = 0; e < 2; ++e) {
            float tctx = w0t[e]*trm[e] + w1t_[e]*tr0[e] + w2t[e]*trp[e] + bt[e];
            float sm = xm[e]-trm[e], s0 = x0v[e]-tr0[e], sp = xp[e]-trp[e];
            float sv = w0s[e]*sm + w1s[e]*s0 + w2s[e]*sp + bs[e];
            float sl = w0l[e]*trm[e] + w1l[e]*tr0[e] + w2l[e]*trp[e] + bl[e];
            sAcc[e] += sl; vAcc[e] += tr0[e];
            u1.h[e] = f2b(tanhf(tctx)); usc.h[e] = f2b(sv);
            trm[e] = tr0[e]; tr0[e] = trp[e]; xm[e] = x0v[e]; x0v[e] = xp[e];
        }
        size_t m = (size_t)b * T_ + t;
        *(unsigned*)&xt[m * C_ + c]   = u1.u;
        *(unsigned*)&sctx[m * C_ + c] = usc.u;
    }
    int pidx = (chunk * B_ + b) * C_ + c;
    *(float2*)&slope_part[pidx] = make_float2(sAcc[0], sAcc[1]);
    *(float2*)&value_part[pidx] = make_float2(vAcc[0], vAcc[1]);
}

// ---------------------------------------------------------------- K2a: pool reduce -> pc[16][1024]
__global__ __launch_bounds__(256) void pool_kernel(
    const float* __restrict__ slope_part, const float* __restrict__ value_part,
    float* __restrict__ pc)
{
    int idx = blockIdx.x * 256 + threadIdx.x;   // 16384
    int b = idx >> 10, j = idx & 1023;
    int c = j & 511;
    const float* src = (j < 512) ? slope_part : value_part;
    float s = 0.f;
    #pragma unroll 8
    for (int ch = 0; ch < NCHUNK; ++ch) s += src[(ch * B_ + b) * C_ + c];
    pc[idx] = s * (1.f / T_);
}

// ---------------------------------------------------------------- K2b: h = silu(pc @ w1 + b1); 1 block per o
__global__ __launch_bounds__(256) void hyper1_kernel(
    const float* __restrict__ pc, const float* __restrict__ w1t,
    const float* __restrict__ b1, float* __restrict__ h)
{
    const int o = blockIdx.x, t = threadIdx.x;
    const float4 w = *(const float4*)&w1t[(size_t)o * 1024 + t * 4];
    float acc[16];
    #pragma unroll
    for (int b = 0; b < 16; ++b) {
        float4 p = *(const float4*)&pc[(size_t)b * 1024 + t * 4];
        acc[b] = w.x * p.x + w.y * p.y + w.z * p.z + w.w * p.w;
    }
    #pragma unroll
    for (int off = 32; off >= 1; off >>= 1)
        #pragma unroll
        for (int b = 0; b < 16; ++b) acc[b] += __shfl_down(acc[b], off);
    __shared__ float red[4][16];
    int lane = t & 63, wv = t >> 6;
    if (lane == 0)
        #pragma unroll
        for (int b = 0; b < 16; ++b) red[wv][b] = acc[b];
    __syncthreads();
    if (t < 16) {
        float s = red[0][t] + red[1][t] + red[2][t] + red[3][t] + b1[o];
        h[(size_t)t * 512 + o] = s / (1.f + expf(-s));
    }
}

// ---------------------------------------------------------------- K2c: params -> dyn_a, dyn_b
__global__ __launch_bounds__(128) void hyper2_kernel(
    const float* __restrict__ h, const float* __restrict__ w2,
    const float* __restrict__ b2, float* __restrict__ dyn_a, float* __restrict__ dyn_b)
{
    __shared__ float pp[16][8];
    const int t = threadIdx.x, b = t >> 3, o = t & 7;
    float acc = b2[o];
    #pragma unroll 4
    for (int j = 0; j < 512; ++j) acc += h[(size_t)b * 512 + j] * w2[j * 8 + o];
    pp[b][o] = acc;
    __syncthreads();
    if (t < 64) {
        int bb = t >> 2, w = t & 3;
        float pa = pp[bb][2 * w], pb = pp[bb][2 * w + 1];
        float sp = fmaxf(pa, 0.f) + log1pf(expf(-fabsf(pa)));
        dyn_a[bb * NW_ + w] = sp + 0.01f;
        dyn_b[bb * NW_ + w] = (1.f / (1.f + expf(-pb))) * (float)T_;
    }
}

// ---------------------------------------------------------------- K2d: psi[m][w] Ricker wavelet
__global__ __launch_bounds__(256) void psi_kernel(
    const float* __restrict__ dyn_a, const float* __restrict__ dyn_b,
    float* __restrict__ psi)
{
    int idx = blockIdx.x * 256 + threadIdx.x;
    int w = idx & 3, m = idx >> 2;
    int b = m >> 10, t = m & 1023;
    float z = ((float)t - dyn_b[b * 4 + w]) / dyn_a[b * 4 + w];
    float z2 = z * z;
    psi[idx] = (1.f - z2) * expf(-0.5f * z2);
}

// ---------------------------------------------------------------- Fused big GEMM: 8-wave 128x256 tile, BK=64
// mode0: tout = powbasis(xt)[M][1536] @ CCT^T + bias0   (A reg-staged, powers in-reg)
// mode1: sout = (psi-scaled sctx)[M][2048] @ WWT^T      (A reg-staged, psi in-reg)
__global__ __launch_bounds__(512, 4) void gemm_big_kernel(
    const bf16* __restrict__ xt, const bf16* __restrict__ sctxg,
    const bf16* __restrict__ CCT, const bf16* __restrict__ WWT,
    const float* __restrict__ psi, const float* __restrict__ bias0,
    bf16* __restrict__ tout, bf16* __restrict__ sout)
{
    __shared__ bf16 lA[128 * 64];   // 16 KB
    __shared__ bf16 lB[256 * 64];   // 32 KB

    const int lin = blockIdx.x;
    const int swz = ((lin & 7) << 6) + (lin >> 3);   // bijective, 512 blocks
    const int mode = swz & 1;
    const int rem = swz >> 1;
    const int nb = rem & 1, mb = rem >> 1;
    const int m0 = mb << 7, n0 = nb << 8;

    const bf16* Ap = mode ? sctxg : xt;
    const bf16* Bp = mode ? WWT : CCT;
    bf16* Cp = mode ? sout : tout;
    const int K = mode ? 2048 : 1536;

    const int tid = threadIdx.x;
    const int lane = tid & 63, wvi = tid >> 6;
    const int wr = wvi >> 2, wc = wvi & 3;          // 2m x 4n waves of 64x64
    const int r16 = lane & 15, g = lane >> 4;
    const int row8 = lane >> 3, sl8 = lane & 7;

    // A reg-staging: 4 threads per row, 16 cols (32 B) each
    const int arow = tid >> 2, quad = tid & 3;
    float4 p4 = make_float4(0.f, 0.f, 0.f, 0.f);
    if (mode) p4 = *(const float4*)&psi[(size_t)(m0 + arow) * 4];

    f4v acc[4][4];
    #pragma unroll
    for (int i = 0; i < 4; ++i)
        #pragma unroll
        for (int j = 0; j < 4; ++j) acc[i][j] = (f4v)0.f;

    const int nK = K >> 6;
    for (int kt = 0; kt < nK; ++kt) {
        const int k0 = kt << 6;
        const int wsel = k0 >> 9;   // power idx (mode0) / wavelet idx (mode1)

        // ---- B stage [256][64]: 4 gload16/thread ----
        #pragma unroll
        for (int c2 = 0; c2 < 4; ++c2) {
            int rb = c2 * 8 + wvi;
            int r = rb * 8 + row8;
            int ls = sl8 ^ (r & 7);
            gload16(Bp + (size_t)(n0 + r) * K + k0 + ls * 8, &lB[rb * 512]);
        }

        // ---- A reg loads (issued before barrier: overlaps prev compute) ----
        const bf16* srcA = Ap + (size_t)(m0 + arow) * 512 + (k0 & 511) + quad * 16;
        s8v av[2];
        av[0] = *(const s8v*)srcA;
        av[1] = *(const s8v*)(srcA + 8);

        __syncthreads();   // prev-iter LDS reads done; B DMA drained (vmcnt 0 at barrier)

        // ---- transform + swizzled ds_write ----
        const float sc = wsel == 0 ? p4.x : wsel == 1 ? p4.y : wsel == 2 ? p4.z : p4.w;
        #pragma unroll
        for (int j2 = 0; j2 < 2; ++j2) {
            s8v ov;
            if (mode == 0) {
                if (wsel == 0) ov = av[j2];
                else {
                    #pragma unroll
                    for (int e = 0; e < 8; ++e) {
                        float v = b2f(((const bf16*)&av[j2])[e]);
                        float vv = v * v;
                        ((bf16*)&ov)[e] = f2b(wsel == 1 ? vv : vv * v);
                    }
                }
            } else {
                #pragma unroll
                for (int e = 0; e < 8; ++e)
                    ((bf16*)&ov)[e] = f2b(b2f(((const bf16*)&av[j2])[e]) * sc);
            }
            int q = quad * 2 + j2;
            *(s8v*)&lA[arow * 64 + ((q ^ (arow & 7)) << 3)] = ov;
        }
        __syncthreads();   // ds_writes visible

        // ---- compute: 2 mfma-K steps of 32 ----
        #pragma unroll
        for (int ks = 0; ks < 2; ++ks) {
            s8v afr[4], bfr[4];
            #pragma unroll
            for (int i = 0; i < 4; ++i) {
                int ar = wr * 64 + i * 16 + r16;
                afr[i] = *(const s8v*)((const char*)lA + ar * 128 + (((ks * 4 + g) ^ (ar & 7)) << 4));
            }
            #pragma unroll
            for (int j = 0; j < 4; ++j) {
                int br = wc * 64 + j * 16 + r16;
                bfr[j] = *(const s8v*)((const char*)lB + br * 128 + (((ks * 4 + g) ^ (br & 7)) << 4));
            }
            #pragma unroll
            for (int i = 0; i < 4; ++i)
                #pragma unroll
                for (int j = 0; j < 4; ++j)
                    acc[i][j] = __builtin_amdgcn_mfma_f32_16x16x32_bf16(afr[i], bfr[j], acc[i][j], 0, 0, 0);
        }
        __syncthreads();   // reads done before next-iter staging
    }

    // ---- C write (D: col=lane&15, row=(lane>>4)*4+r), + bias on mode0 ----
    #pragma unroll
    for (int i = 0; i < 4; ++i)
        #pragma unroll
        for (int j = 0; j < 4; ++j) {
            int cc = n0 + wc * 64 + j * 16 + r16;
            float bb = (mode == 0) ? bias0[cc] : 0.f;
            #pragma unroll
            for (int r = 0; r < 4; ++r) {
                int rr = m0 + wr * 64 + i * 16 + g * 4 + r;
                Cp[(size_t)rr * 512 + cc] = f2b(acc[i][j][r] + bb);
            }
        }
}

// ---------------------------------------------------------------- Fused amp-GEMM + gate + residual + LayerNorm
// BM=64, BN=512 (full rows), 8 waves; ampin never materialized.
__global__ __launch_bounds__(512, 2) void amp_ln_kernel(
    const bf16* __restrict__ tout, const bf16* __restrict__ sout,
    const bf16* __restrict__ AWT,  const float* __restrict__ ampb,
    const float* __restrict__ x,   const float* __restrict__ gamma,
    const float* __restrict__ beta, float* __restrict__ out)
{
    __shared__ bf16 lA[64 * 64];     // 8 KB
    __shared__ bf16 lB[512 * 64];    // 64 KB
    __shared__ float red[64 * 16];   // 4 KB

    const int m0 = blockIdx.x << 6;
    const int tid = threadIdx.x;
    const int lane = tid & 63, wvi = tid >> 6;
    const int wc = wvi;                     // n-offset wc*64
    const int r16 = lane & 15, g = lane >> 4;
    const int row8 = lane >> 3, sl8 = lane & 7;

    f4v acc[4][4];
    #pragma unroll
    for (int i = 0; i < 4; ++i)
        #pragma unroll
        for (int j = 0; j < 4; ++j) acc[i][j] = (f4v)0.f;

    for (int kt = 0; kt < 8; ++kt) {
        const int k0 = kt << 6;
        // A stage [64][64]: 1 gload16/thread
        {
            int r = (wvi << 3) + row8;
            int ls = sl8 ^ (r & 7);
            gload16(tout + (size_t)(m0 + r) * 512 + k0 + ls * 8, &lA[wvi * 512]);
        }
        // B stage [512][64]: 8 gload16/thread
        #pragma unroll
        for (int c2 = 0; c2 < 8; ++c2) {
            int r = c2 * 64 + (wvi << 3) + row8;
            int ls = sl8 ^ (r & 7);
            gload16(AWT + (size_t)r * 512 + k0 + ls * 8, &lB[c2 * 4096 + wvi * 512]);
        }
        __syncthreads();
        #pragma unroll
        for (int ks = 0; ks < 2; ++ks) {
            s8v afr[4], bfr[4];
            #pragma unroll
            for (int i = 0; i < 4; ++i) {
                int ar = i * 16 + r16;
                afr[i] = *(const s8v*)((const char*)lA + ar * 128 + (((ks * 4 + g) ^ (ar & 7)) << 4));
            }
            #pragma unroll
            for (int j = 0; j < 4; ++j) {
                int br = wc * 64 + j * 16 + r16;
                bfr[j] = *(const s8v*)((const char*)lB + br * 128 + (((ks * 4 + g) ^ (br & 7)) << 4));
            }
            #pragma unroll
            for (int i = 0; i < 4; ++i)
                #pragma unroll
                for (int j = 0; j < 4; ++j)
                    acc[i][j] = __builtin_amdgcn_mfma_f32_16x16x32_bf16(afr[i], bfr[j], acc[i][j], 0, 0, 0);
        }
        __syncthreads();
    }

    // ---- epilogue: amp gate + residual; y overwrites acc ----
    float ab[4], gm[4], bt2[4];
    #pragma unroll
    for (int j = 0; j < 4; ++j) {
        int cc = wc * 64 + j * 16 + r16;
        ab[j] = ampb[cc]; gm[j] = gamma[cc]; bt2[j] = beta[cc];
    }
    f4v s4[4], q4[4];
    #pragma unroll
    for (int i = 0; i < 4; ++i) { s4[i] = (f4v)0.f; q4[i] = (f4v)0.f; }

    #pragma unroll
    for (int i = 0; i < 4; ++i)
        #pragma unroll
        for (int j = 0; j < 4; ++j) {
            int cc = wc * 64 + j * 16 + r16;
            #pragma unroll
            for (int r = 0; r < 4; ++r) {
                size_t rr = (size_t)(m0 + i * 16 + g * 4 + r);
                float amp = 2.f / (1.f + expf(-(acc[i][j][r] + ab[j])));
                float y = b2f(tout[rr * 512 + cc]) + b2f(sout[rr * 512 + cc]) * amp + x[rr * 512 + cc];
                acc[i][j][r] = y;
                s4[i][r] += y; q4[i][r] += y * y;
            }
        }

    // reduce over the 16-lane r16 group (same rows)
    #pragma unroll
    for (int off = 1; off < 16; off <<= 1)
        #pragma unroll
        for (int i = 0; i < 4; ++i)
            #pragma unroll
            for (int r = 0; r < 4; ++r) {
                s4[i][r] += __shfl_xor(s4[i][r], off);
                q4[i][r] += __shfl_xor(q4[i][r], off);
            }
    if (r16 == 0) {
        #pragma unroll
        for (int i = 0; i < 4; ++i)
            #pragma unroll
            for (int r = 0; r < 4; ++r) {
                int row = i * 16 + g * 4 + r;
                red[row * 16 + wvi * 2]     = s4[i][r];
                red[row * 16 + wvi * 2 + 1] = q4[i][r];
            }
    }
    __syncthreads();
    if (tid < 64) {
        float ts = 0.f, tq = 0.f;
        #pragma unroll
        for (int w = 0; w < 8; ++w) { ts += red[tid * 16 + w * 2]; tq += red[tid * 16 + w * 2 + 1]; }
        float mu = ts * (1.f / 512.f);
        float var = tq * (1.f / 512.f) - mu * mu;
        red[tid * 16]     = mu;
        red[tid * 16 + 1] = rsqrtf(var + 1e-5f);
    }
    __syncthreads();

    #pragma unroll
    for (int i = 0; i < 4; ++i)
        #pragma unroll
        for (int r = 0; r < 4; ++r) {
            int row = i * 16 + g * 4 + r;
            float mu = red[row * 16], rs = red[row * 16 + 1];
            size_t rr = (size_t)(m0 + row);
            #pragma unroll
            for (int j = 0; j < 4; ++j) {
                int cc = wc * 64 + j * 16 + r16;
                out[rr * 512 + cc] = (acc[i][j][r] - mu) * rs * gm[j] + bt2[j];
            }
        }
}

// ----------------------------------------------------------------
extern "C" void kernel_launch(void* const* d_in, const int* in_sizes, int n_in,
                              void* d_out, int out_size, void* d_ws, size_t ws_size,
                              hipStream_t stream)
{
    const float* x     = (const float*)d_in[0];
    const float* tcw   = (const float*)d_in[1];
    const float* tcb   = (const float*)d_in[2];
    const float* scw   = (const float*)d_in[3];
    const float* scb   = (const float*)d_in[4];
    const float* lcw   = (const float*)d_in[5];
    const float* lcb   = (const float*)d_in[6];
    const float* cheby = (const float*)d_in[7];
    const float* hw1   = (const float*)d_in[8];
    const float* hb1   = (const float*)d_in[9];
    const float* hw2   = (const float*)d_in[10];
    const float* hb2   = (const float*)d_in[11];
    const float* ampw  = (const float*)d_in[12];
    const float* ampb  = (const float*)d_in[13];
    const float* wav   = (const float*)d_in[14];
    const float* lng   = (const float*)d_in[15];
    const float* lnb   = (const float*)d_in[16];
    float* out = (float*)d_out;

    char* ws = (char*)d_ws;
    size_t off = 0;
    auto alloc = [&](size_t bytes) -> char* {
        char* p = ws + off;
        off += (bytes + 255) & ~(size_t)255;
        return p;
    };
    bf16*  xt         = (bf16*)alloc((size_t)M_ * 512 * 2);
    bf16*  sctx       = (bf16*)alloc((size_t)M_ * 512 * 2);
    bf16*  tout       = (bf16*)alloc((size_t)M_ * 512 * 2);
    bf16*  sout       = (bf16*)alloc((size_t)M_ * 512 * 2);
    bf16*  CCT        = (bf16*)alloc((size_t)512 * 1536 * 2);
    bf16*  WWT        = (bf16*)alloc((size_t)512 * 2048 * 2);
    bf16*  AWT        = (bf16*)alloc((size_t)512 * 512 * 2);
    float* W1T        = (float*)alloc((size_t)512 * 1024 * 4);
    float* bias0      = (float*)alloc(512 * 4);
    float* slope_part = (float*)alloc((size_t)NCHUNK * B_ * C_ * 4);
    float* value_part = (float*)alloc((size_t)NCHUNK * B_ * C_ * 4);
    float* pc         = (float*)alloc(B_ * 1024 * 4);
    float* hbuf       = (float*)alloc(B_ * C_ * 4);
    float* dyn_a      = (float*)alloc(B_ * NW_ * 4);
    float* dyn_b      = (float*)alloc(B_ * NW_ * 4);
    float* psi        = (float*)alloc((size_t)M_ * NW_ * 4);

    repack_t_kernel<<<dim3(16, 16, 5), 256, 0, stream>>>(wav, ampw, WWT, AWT);
    repack_cct_kernel<<<dim3(16, 16), 256, 0, stream>>>(cheby, CCT);
    bias0_kernel<<<16, 256, 0, stream>>>(cheby, bias0);
    transpose_w1_kernel<<<dim3(16, 32), 256, 0, stream>>>(hw1, W1T);
    decomp_kernel<<<dim3(NCHUNK, B_), 256, 0, stream>>>(x, tcw, tcb, scw, scb, lcw, lcb,
                                                        xt, sctx, slope_part, value_part);
    pool_kernel<<<64, 256, 0, stream>>>(slope_part, value_part, pc);
    hyper1_kernel<<<512, 256, 0, stream>>>(pc, W1T, hb1, hbuf);
    hyper2_kernel<<<1, 128, 0, stream>>>(hbuf, hw2, hb2, dyn_a, dyn_b);
    psi_kernel<<<256, 256, 0, stream>>>(dyn_a, dyn_b, psi);
    gemm_big_kernel<<<512, 512, 0, stream>>>(xt, sctx, CCT, WWT, psi, bias0, tout, sout);
    amp_ln_kernel<<<256, 512, 0, stream>>>(tout, sout, AWT, ampb, x, lng, lnb, out);
}